// Round 1
// 407.883 us; speedup vs baseline: 1.0471x; 1.0471x over previous
//
#include <hip/hip_runtime.h>
#include <hip/hip_bf16.h>
#include <stdint.h>

// WaveletLinearLayer: out = HaarDWT2(x) @ W.T + b
// == split GEMM: out[m,n] = b[n] + 0.5 * sum_k u[m,k]*W[n,k],
// u = unscaled Haar combos of 2x2 spatial quads of x. M=256,N=64,K=262144.
//
// R4: persistent blocks + sequential streams + reg-pipelined staging.
// R5: (a) XCD-aware sibling remap — the 4 mh-siblings sharing a 512KB W
//     slice are placed on the SAME XCD (HW maps blockIdx%8 -> XCD) at
//     consecutive slots, so W is fetched into that XCD's L2 once and hit
//     3x instead of 4 XCDs each pulling it from L3/HBM (-192MB requests).
//     (b) nontemporal x loads (zero reuse) so the 256MB x stream doesn't
//     evict the W slices from L2. (c) nontemporal partial stores.

#define IN_K  262144
#define PITCH 264   // LDS row pitch in shorts; 264 = 4 mod 32 banks -> 2-way max

typedef short bf16x8 __attribute__((ext_vector_type(8)));
typedef float f32x4  __attribute__((ext_vector_type(4)));

__device__ __forceinline__ uint32_t pack2_bf16(float a, float b) {
    uint32_t ua = __float_as_uint(a);
    uint32_t ub = __float_as_uint(b);
    ua = (ua + 0x7fffu + ((ua >> 16) & 1u)) >> 16;
    ub = (ub + 0x7fffu + ((ub >> 16) & 1u)) >> 16;
    return ua | (ub << 16);
}

__global__ __launch_bounds__(512, 4) void wavelet_gemm(
    const float* __restrict__ x, const float* __restrict__ W,
    float* __restrict__ part)
{
    __shared__ short Ash[64 * PITCH];   // u[m_l][k] bf16, 33792 B
    __shared__ short Bsh[64 * PITCH];   // W[n][k]  bf16, 33792 B

    const int tid  = threadIdx.x;
    const int lane = tid & 63;
    const int l16  = lane & 15;
    const int l4   = lane >> 4;
    const int wave = tid >> 6;          // 8 waves

    // XCD-aware remap: xcd = b&7 (HW round-robin), slot = b>>3 within XCD.
    // Siblings (same widx, mh=0..3) -> same XCD, consecutive slots. All
    // 512 blocks co-resident (2/CU), so siblings stream W concurrently.
    const int b    = blockIdx.x;        // 512 blocks
    const int slot = b >> 3;            // 0..63
    const int mh   = slot & 3;
    const int widx = (b & 7) + 8 * (slot >> 2);  // 0..127
    const int c    = widx >> 5;         // channel 0..3
    const int ig   = widx & 31;         // i-group: i = 4*ig .. 4*ig+3

    const float* xm  = x + (size_t)(mh * 64) * IN_K + c * 65536;
    const float* wcb = W + c * 65536;

    // per-thread invariant staging coords
    const int a_m  = tid >> 5;          // A: m_l = a_m + 16*r
    const int a_j4 = tid & 31;          // float4 index in 128-col chunk
    const int b_n  = tid >> 4;          // B: n = b_n + 32*r
    const int b_j  = tid & 15;          // jlq

    f32x4 af[4][2];                     // A load buffer (32 VGPRs)
    f32x4 bf[2][4];                     // B load buffer (32 VGPRs)

    auto load_chunk = [&](int t) {
        const int i  = ig * 4 + (t >> 1);
        const int jh = t & 1;
        const float* xc = xm + 2 * i * 256 + 128 * jh;
#pragma unroll
        for (int r = 0; r < 4; r++) {
            const float* xp = xc + (size_t)(a_m + 16 * r) * IN_K + 4 * a_j4;
            af[r][0] = __builtin_nontemporal_load((const f32x4*)(xp));        // row 2i
            af[r][1] = __builtin_nontemporal_load((const f32x4*)(xp + 256));  // row 2i+1
        }
        const float* wc = wcb + i * 128 + 64 * jh;
#pragma unroll
        for (int r = 0; r < 2; r++) {
            const float* wp = wc + (size_t)(b_n + 32 * r) * IN_K + 4 * b_j;
            bf[r][0] = *(const f32x4*)(wp);            // keep cached: 4x reuse via L2
            bf[r][1] = *(const f32x4*)(wp + 16384);
            bf[r][2] = *(const f32x4*)(wp + 32768);
            bf[r][3] = *(const f32x4*)(wp + 49152);
        }
    };

    auto stage = [&]() {
#pragma unroll
        for (int r = 0; r < 4; r++) {
            const f32x4 f0 = af[r][0], f1 = af[r][1];
            const float s1 = f0[0] + f0[1], d1 = f0[0] - f0[1];
            const float s2 = f1[0] + f1[1], d2 = f1[0] - f1[1];
            const float t1 = f0[2] + f0[3], e1 = f0[2] - f0[3];
            const float t2 = f1[2] + f1[3], e2 = f1[2] - f1[3];
            union { bf16x8 v; uint32_t u[4]; } au;
            au.u[0] = pack2_bf16(s1 + s2, s1 - s2);  // k=8j4+0,1 (LL,LH q1)
            au.u[1] = pack2_bf16(d1 + d2, d1 - d2);  // k=8j4+2,3 (HL,HH)
            au.u[2] = pack2_bf16(t1 + t2, t1 - t2);  // quad2
            au.u[3] = pack2_bf16(e1 + e2, e1 - e2);
            *(bf16x8*)&Ash[(a_m + 16 * r) * PITCH + 8 * a_j4] = au.v;
        }
#pragma unroll
        for (int r = 0; r < 2; r++) {
            const f32x4 v0 = bf[r][0], v1 = bf[r][1];
            const f32x4 v2 = bf[r][2], v3 = bf[r][3];
            union { bf16x8 v; uint32_t u[4]; } b0, b1;
            b0.u[0] = pack2_bf16(v0[0], v1[0]);  // k=16jlq+0,1
            b0.u[1] = pack2_bf16(v2[0], v3[0]);  // k=16jlq+2,3
            b0.u[2] = pack2_bf16(v0[1], v1[1]);
            b0.u[3] = pack2_bf16(v2[1], v3[1]);
            b1.u[0] = pack2_bf16(v0[2], v1[2]);
            b1.u[1] = pack2_bf16(v2[2], v3[2]);
            b1.u[2] = pack2_bf16(v0[3], v1[3]);
            b1.u[3] = pack2_bf16(v2[3], v3[3]);
            short* br = &Bsh[(b_n + 32 * r) * PITCH + 16 * b_j];
            *(bf16x8*)(br)     = b0.v;
            *(bf16x8*)(br + 8) = b1.v;
        }
    };

    const int tm = wave & 3;     // m-tile within 64
    const int nh = wave >> 2;    // n-half
    f32x4 acc0 = (f32x4){0.f, 0.f, 0.f, 0.f};
    f32x4 acc1 = (f32x4){0.f, 0.f, 0.f, 0.f};

    load_chunk(0);
#pragma unroll 1
    for (int t = 0; t < 8; t++) {
        stage();
        __syncthreads();
        if (t < 7) load_chunk(t + 1);   // in flight during MFMA + barrier
#pragma unroll
        for (int kh = 0; kh < 8; kh++) {
            const int ko = kh * 32 + l4 * 8;
            bf16x8 a  = *(const bf16x8*)&Ash[(tm * 16 + l16) * PITCH + ko];
            bf16x8 bb0 = *(const bf16x8*)&Bsh[(nh * 32 + l16) * PITCH + ko];
            bf16x8 bb1 = *(const bf16x8*)&Bsh[(nh * 32 + 16 + l16) * PITCH + ko];
            acc0 = __builtin_amdgcn_mfma_f32_16x16x32_bf16(a, bb0, acc0, 0, 0, 0);
            acc1 = __builtin_amdgcn_mfma_f32_16x16x32_bf16(a, bb1, acc1, 0, 0, 0);
        }
        __syncthreads();
    }

    // ---- write 64x64 fp32 partial, indexed by LOGICAL (widx,mh) so the
    // reduce kernel's layout is unchanged. (C/D: col=lane&15, row=(lane>>4)*4+r)
    float* pp = part + (size_t)(widx * 4 + mh) * 4096;
#pragma unroll
    for (int r = 0; r < 4; r++) {
        const int m = tm * 16 + l4 * 4 + r;
        __builtin_nontemporal_store(acc0[r], &pp[m * 64 + nh * 32 + l16]);
        __builtin_nontemporal_store(acc1[r], &pp[m * 64 + nh * 32 + 16 + l16]);
    }
}

// out[m][n] = bias[n] + 0.5 * sum_{w=0}^{127} part[(w*4 + m>>6)][m&63][n]
__global__ __launch_bounds__(256) void wavelet_reduce(
    const float* __restrict__ part, const float* __restrict__ bias,
    float* __restrict__ out)
{
    __shared__ float red[4][64];
    const int m  = blockIdx.x;          // 256
    const int mh = m >> 6;
    const int ml = m & 63;
    const int n  = threadIdx.x & 63;
    const int g  = threadIdx.x >> 6;    // 4 groups
    const float* base = part + (size_t)mh * 4096 + ml * 64 + n;
    float acc = 0.f;
#pragma unroll 4
    for (int w = g; w < 128; w += 4)
        acc += base[(size_t)w * 16384];
    red[g][n] = acc;
    __syncthreads();
    if (g == 0) {
        const float v = red[0][n] + red[1][n] + red[2][n] + red[3][n];
        out[m * 64 + n] = 0.5f * v + bias[n];
    }
}

extern "C" void kernel_launch(void* const* d_in, const int* in_sizes, int n_in,
                              void* d_out, int out_size, void* d_ws, size_t ws_size,
                              hipStream_t stream)
{
    const float* x = (const float*)d_in[0];   // (256, 262144) fp32
    const float* W = (const float*)d_in[1];   // (64, 262144) fp32
    const float* b = (const float*)d_in[2];   // (64,) fp32
    float* out  = (float*)d_out;              // (256, 64) fp32
    float* part = (float*)d_ws;               // 512 * 16 KB = 8 MB

    wavelet_gemm<<<512, 512, 0, stream>>>(x, W, part);
    wavelet_reduce<<<256, 256, 0, stream>>>(part, b, out);
}

// Round 3
// 405.354 us; speedup vs baseline: 1.0536x; 1.0062x over previous
//
#include <hip/hip_runtime.h>
#include <hip/hip_bf16.h>
#include <stdint.h>

// WaveletLinearLayer: out = HaarDWT2(x) @ W.T + b
// == split GEMM: out[m,n] = b[n] + 0.5 * sum_k u[m,k]*W[n,k],
// u = unscaled Haar combos of 2x2 spatial quads of x. M=256,N=64,K=262144.
//
// R4: persistent blocks + sequential streams + reg-pipelined staging.
// R5: XCD-aware sibling remap (W slice L2-shared by 4 mh-siblings on one
//     XCD), nontemporal x loads + partial stores.            [-19 us]
// R6: FAILED — 16 MB partials overflowed the 8 MB workspace budget
//     (post-timing deterministic divergence = neighbor-buffer corruption).
//     Also: 4 blocks/CU gave ZERO timing delta -> occupancy/barrier-latency
//     is NOT the gemm limiter. Constraint recorded: part <= 8 MB.
// R7: revert to R5 gemm verbatim (proven pass, 8 MB). Reduce kernel to
//     512 threads (8 groups) to halve its strided-read depth.

#define IN_K  262144
#define PITCH 264   // LDS row pitch in shorts; 264 = 4 mod 32 banks -> 2-way max

typedef short bf16x8 __attribute__((ext_vector_type(8)));
typedef float f32x4  __attribute__((ext_vector_type(4)));

__device__ __forceinline__ uint32_t pack2_bf16(float a, float b) {
    uint32_t ua = __float_as_uint(a);
    uint32_t ub = __float_as_uint(b);
    ua = (ua + 0x7fffu + ((ua >> 16) & 1u)) >> 16;
    ub = (ub + 0x7fffu + ((ub >> 16) & 1u)) >> 16;
    return ua | (ub << 16);
}

__global__ __launch_bounds__(512, 4) void wavelet_gemm(
    const float* __restrict__ x, const float* __restrict__ W,
    float* __restrict__ part)
{
    __shared__ short Ash[64 * PITCH];   // u[m_l][k] bf16, 33792 B
    __shared__ short Bsh[64 * PITCH];   // W[n][k]  bf16, 33792 B

    const int tid  = threadIdx.x;
    const int lane = tid & 63;
    const int l16  = lane & 15;
    const int l4   = lane >> 4;
    const int wave = tid >> 6;          // 8 waves

    // XCD-aware remap: xcd = b&7 (HW round-robin), slot = b>>3 within XCD.
    // Siblings (same widx, mh=0..3) -> same XCD, consecutive slots; all
    // 512 blocks co-resident (2/CU), so siblings stream W concurrently.
    const int b    = blockIdx.x;        // 512 blocks
    const int slot = b >> 3;            // 0..63
    const int mh   = slot & 3;
    const int widx = (b & 7) + 8 * (slot >> 2);  // 0..127
    const int c    = widx >> 5;         // channel 0..3
    const int ig   = widx & 31;         // i-group: i = 4*ig .. 4*ig+3

    const float* xm  = x + (size_t)(mh * 64) * IN_K + c * 65536;
    const float* wcb = W + c * 65536;

    // per-thread invariant staging coords
    const int a_m  = tid >> 5;          // A: m_l = a_m + 16*r
    const int a_j4 = tid & 31;          // float4 index in 128-col chunk
    const int b_n  = tid >> 4;          // B: n = b_n + 32*r
    const int b_j  = tid & 15;          // jlq

    f32x4 af[4][2];                     // A load buffer (32 VGPRs)
    f32x4 bf[2][4];                     // B load buffer (32 VGPRs)

    auto load_chunk = [&](int t) {
        const int i  = ig * 4 + (t >> 1);
        const int jh = t & 1;
        const float* xc = xm + 2 * i * 256 + 128 * jh;
#pragma unroll
        for (int r = 0; r < 4; r++) {
            const float* xp = xc + (size_t)(a_m + 16 * r) * IN_K + 4 * a_j4;
            af[r][0] = __builtin_nontemporal_load((const f32x4*)(xp));        // row 2i
            af[r][1] = __builtin_nontemporal_load((const f32x4*)(xp + 256));  // row 2i+1
        }
        const float* wc = wcb + i * 128 + 64 * jh;
#pragma unroll
        for (int r = 0; r < 2; r++) {
            const float* wp = wc + (size_t)(b_n + 32 * r) * IN_K + 4 * b_j;
            bf[r][0] = *(const f32x4*)(wp);            // keep L2-cached: 4x sibling reuse
            bf[r][1] = *(const f32x4*)(wp + 16384);
            bf[r][2] = *(const f32x4*)(wp + 32768);
            bf[r][3] = *(const f32x4*)(wp + 49152);
        }
    };

    auto stage = [&]() {
#pragma unroll
        for (int r = 0; r < 4; r++) {
            const f32x4 f0 = af[r][0], f1 = af[r][1];
            const float s1 = f0[0] + f0[1], d1 = f0[0] - f0[1];
            const float s2 = f1[0] + f1[1], d2 = f1[0] - f1[1];
            const float t1 = f0[2] + f0[3], e1 = f0[2] - f0[3];
            const float t2 = f1[2] + f1[3], e2 = f1[2] - f1[3];
            union { bf16x8 v; uint32_t u[4]; } au;
            au.u[0] = pack2_bf16(s1 + s2, s1 - s2);  // k=8j4+0,1 (LL,LH of j0)
            au.u[1] = pack2_bf16(d1 + d2, d1 - d2);  // k=8j4+2,3 (HL,HH of j0)
            au.u[2] = pack2_bf16(t1 + t2, t1 - t2);  // j1
            au.u[3] = pack2_bf16(e1 + e2, e1 - e2);
            *(bf16x8*)&Ash[(a_m + 16 * r) * PITCH + 8 * a_j4] = au.v;
        }
#pragma unroll
        for (int r = 0; r < 2; r++) {
            const f32x4 v0 = bf[r][0], v1 = bf[r][1];
            const f32x4 v2 = bf[r][2], v3 = bf[r][3];
            union { bf16x8 v; uint32_t u[4]; } b0, b1;
            b0.u[0] = pack2_bf16(v0[0], v1[0]);  // k=16jlq+0,1
            b0.u[1] = pack2_bf16(v2[0], v3[0]);  // k=16jlq+2,3
            b0.u[2] = pack2_bf16(v0[1], v1[1]);
            b0.u[3] = pack2_bf16(v2[1], v3[1]);
            b1.u[0] = pack2_bf16(v0[2], v1[2]);
            b1.u[1] = pack2_bf16(v2[2], v3[2]);
            b1.u[2] = pack2_bf16(v0[3], v1[3]);
            b1.u[3] = pack2_bf16(v2[3], v3[3]);
            short* br = &Bsh[(b_n + 32 * r) * PITCH + 16 * b_j];
            *(bf16x8*)(br)     = b0.v;
            *(bf16x8*)(br + 8) = b1.v;
        }
    };

    const int tm = wave & 3;     // m-tile within 64
    const int nh = wave >> 2;    // n-half
    f32x4 acc0 = (f32x4){0.f, 0.f, 0.f, 0.f};
    f32x4 acc1 = (f32x4){0.f, 0.f, 0.f, 0.f};

    load_chunk(0);
#pragma unroll 1
    for (int t = 0; t < 8; t++) {
        stage();
        __syncthreads();
        if (t < 7) load_chunk(t + 1);   // in flight during MFMA + barrier
#pragma unroll
        for (int kh = 0; kh < 8; kh++) {
            const int ko = kh * 32 + l4 * 8;
            bf16x8 a  = *(const bf16x8*)&Ash[(tm * 16 + l16) * PITCH + ko];
            bf16x8 bb0 = *(const bf16x8*)&Bsh[(nh * 32 + l16) * PITCH + ko];
            bf16x8 bb1 = *(const bf16x8*)&Bsh[(nh * 32 + 16 + l16) * PITCH + ko];
            acc0 = __builtin_amdgcn_mfma_f32_16x16x32_bf16(a, bb0, acc0, 0, 0, 0);
            acc1 = __builtin_amdgcn_mfma_f32_16x16x32_bf16(a, bb1, acc1, 0, 0, 0);
        }
        __syncthreads();
    }

    // ---- write 64x64 fp32 partial, indexed by LOGICAL (widx,mh) so the
    // reduce kernel's layout is fixed. (C/D: col=lane&15, row=(lane>>4)*4+r)
    float* pp = part + (size_t)(widx * 4 + mh) * 4096;
#pragma unroll
    for (int r = 0; r < 4; r++) {
        const int m = tm * 16 + l4 * 4 + r;
        __builtin_nontemporal_store(acc0[r], &pp[m * 64 + nh * 32 + l16]);
        __builtin_nontemporal_store(acc1[r], &pp[m * 64 + nh * 32 + 16 + l16]);
    }
}

// out[m][n] = bias[n] + 0.5 * sum_{w=0}^{127} part[(w*4 + m>>6)][m&63][n]
__global__ __launch_bounds__(512) void wavelet_reduce(
    const float* __restrict__ part, const float* __restrict__ bias,
    float* __restrict__ out)
{
    __shared__ float red[8][64];
    const int m  = blockIdx.x;          // 256
    const int mh = m >> 6;
    const int ml = m & 63;
    const int n  = threadIdx.x & 63;
    const int g  = threadIdx.x >> 6;    // 8 groups
    const float* base = part + (size_t)mh * 4096 + ml * 64 + n;
    float acc = 0.f;
#pragma unroll 4
    for (int w = g; w < 128; w += 8)
        acc += base[(size_t)w * 16384];
    red[g][n] = acc;
    __syncthreads();
    if (g == 0) {
        const float v = (red[0][n] + red[1][n]) + (red[2][n] + red[3][n])
                      + (red[4][n] + red[5][n]) + (red[6][n] + red[7][n]);
        out[m * 64 + n] = 0.5f * v + bias[n];
    }
}

extern "C" void kernel_launch(void* const* d_in, const int* in_sizes, int n_in,
                              void* d_out, int out_size, void* d_ws, size_t ws_size,
                              hipStream_t stream)
{
    const float* x = (const float*)d_in[0];   // (256, 262144) fp32
    const float* W = (const float*)d_in[1];   // (64, 262144) fp32
    const float* b = (const float*)d_in[2];   // (64,) fp32
    float* out  = (float*)d_out;              // (256, 64) fp32
    float* part = (float*)d_ws;               // 512 * 16 KB = 8 MB (ws budget!)

    wavelet_gemm<<<512, 512, 0, stream>>>(x, W, part);
    wavelet_reduce<<<256, 512, 0, stream>>>(part, b, out);
}

// Round 4
// 403.501 us; speedup vs baseline: 1.0584x; 1.0046x over previous
//
#include <hip/hip_runtime.h>
#include <hip/hip_bf16.h>
#include <stdint.h>

// WaveletLinearLayer: out = HaarDWT2(x) @ W.T + b
// == split GEMM: out[m,n] = b[n] + 0.5 * sum_k u[m,k]*W[n,k],
// u = unscaled Haar combos of 2x2 spatial quads of x. M=256,N=64,K=262144.
//
// R4: persistent blocks + sequential streams + reg-pipelined staging.
// R5: XCD-aware sibling remap (W L2-shared by 4 mh-siblings/XCD), nt loads.
// R6: FAILED (16MB partials > 8MB ws budget). Also: 4 blk/CU == 2 blk/CU
//     -> occupancy is NOT the gemm limiter.
// R7: revert to R5; gemm ~81us = 4.15 TB/s = 66% of fill-rate.
// R8: DRAM page-efficiency fix for the x stream (76% of traffic).
//     Old: each 2KB row-pair page read as 2x512B now + 2x512B a chunk
//     later (2 activates/page, 512B each). New: wave owns 8 m-rows, loads
//     FULL rows (1KB contiguous per instr, 2KB sequential per row-pair)
//     once per phase; one stage fills TWO A LDS buffers (lanes 0-31 ->
//     chunk 2p, lanes 32-63 -> chunk 2p+1). af 32->64 VGPR, LDS 99KB ->
//     1 block/CU (R6 says occupancy doesn't matter). A-load lead grows
//     to ~2 chunks. B path / MFMA / partials / reduce unchanged.

#define IN_K  262144
#define PITCH 264   // LDS row pitch in shorts; 264 = 4 mod 32 banks -> 2-way max

typedef short bf16x8 __attribute__((ext_vector_type(8)));
typedef float f32x4  __attribute__((ext_vector_type(4)));

__device__ __forceinline__ uint32_t pack2_bf16(float a, float b) {
    uint32_t ua = __float_as_uint(a);
    uint32_t ub = __float_as_uint(b);
    ua = (ua + 0x7fffu + ((ua >> 16) & 1u)) >> 16;
    ub = (ub + 0x7fffu + ((ub >> 16) & 1u)) >> 16;
    return ua | (ub << 16);
}

__global__ __launch_bounds__(512, 2) void wavelet_gemm(
    const float* __restrict__ x, const float* __restrict__ W,
    float* __restrict__ part)
{
    __shared__ short Ash[2][64 * PITCH];  // chunk 2p / 2p+1 A tiles, 33792 B each
    __shared__ short Bsh[64 * PITCH];     // W[n][k] bf16, 33792 B

    const int tid  = threadIdx.x;
    const int lane = tid & 63;
    const int l16  = lane & 15;
    const int l4   = lane >> 4;
    const int wave = tid >> 6;          // 8 waves

    // XCD-aware remap: xcd = b&7 (HW round-robin), slot = b>>3 within XCD.
    // Siblings (same widx, mh=0..3) -> same XCD, consecutive slots.
    const int b    = blockIdx.x;        // 512 blocks
    const int slot = b >> 3;            // 0..63
    const int mh   = slot & 3;
    const int widx = (b & 7) + 8 * (slot >> 2);  // 0..127
    const int c    = widx >> 5;         // channel 0..3
    const int ig   = widx & 31;         // i-group: i = 4*ig .. 4*ig+3

    const float* xm  = x + (size_t)(mh * 64) * IN_K + c * 65536;
    const float* wcb = W + c * 65536;

    // A: wave owns m-rows 8*wave .. 8*wave+7; lane l holds cols 4l..4l+3
    const int a_m0 = wave << 3;
    // B staging coords (unchanged from R5/R7)
    const int b_n  = tid >> 4;          // n = b_n + 32*r
    const int b_j  = tid & 15;          // jlq

    f32x4 af[8][2];                     // A buffer: 8 m-rows x full row-pair (64 VGPR)
    f32x4 bf[2][4];                     // B buffer (32 VGPR)

    // phase p: i = ig*4 + p. Full row-pair, 1KB-contiguous wave granules,
    // af[r][0]/af[r][1] adjacent -> 2KB sequential per m-row.
    auto load_A = [&](int p) {
        const int i = ig * 4 + p;
#pragma unroll
        for (int r = 0; r < 8; r++) {
            const float* xp = xm + (size_t)(a_m0 + r) * IN_K + 2 * i * 256 + 4 * lane;
            af[r][0] = __builtin_nontemporal_load((const f32x4*)(xp));        // row 2i
            af[r][1] = __builtin_nontemporal_load((const f32x4*)(xp + 256));  // row 2i+1
        }
    };

    // B for chunk t (t=0..7): i = ig*4 + (t>>1), jh = t&1 (unchanged)
    auto load_B = [&](int t) {
        const int i  = ig * 4 + (t >> 1);
        const int jh = t & 1;
        const float* wc = wcb + i * 128 + 64 * jh;
#pragma unroll
        for (int r = 0; r < 2; r++) {
            const float* wp = wc + (size_t)(b_n + 32 * r) * IN_K + 4 * b_j;
            bf[r][0] = *(const f32x4*)(wp);            // L2-cached: 4x sibling reuse
            bf[r][1] = *(const f32x4*)(wp + 16384);
            bf[r][2] = *(const f32x4*)(wp + 32768);
            bf[r][3] = *(const f32x4*)(wp + 49152);
        }
    };

    // One stage fills BOTH A buffers: lane l<32 -> Ash[0] (cols 0..127,
    // chunk 2p), lane>=32 -> Ash[1] (cols 128..255, chunk 2p+1).
    // Per lane: col-pairs 2*(l&31), 2*(l&31)+1 -> k_local 8*(l&31)+0..7,
    // k_local = 4*cp_local + band (same convention as B).
    auto stage_A = [&]() {
        short* dst = &Ash[lane >> 5][0];
        const int kofs = 8 * (lane & 31);
#pragma unroll
        for (int r = 0; r < 8; r++) {
            const f32x4 f0 = af[r][0], f1 = af[r][1];
            const float s1 = f0[0] + f0[1], d1 = f0[0] - f0[1];
            const float s2 = f1[0] + f1[1], d2 = f1[0] - f1[1];
            const float t1 = f0[2] + f0[3], e1 = f0[2] - f0[3];
            const float t2 = f1[2] + f1[3], e2 = f1[2] - f1[3];
            union { bf16x8 v; uint32_t u[4]; } au;
            au.u[0] = pack2_bf16(s1 + s2, s1 - s2);  // LL,LH of cp0
            au.u[1] = pack2_bf16(d1 + d2, d1 - d2);  // HL,HH of cp0
            au.u[2] = pack2_bf16(t1 + t2, t1 - t2);  // LL,LH of cp1
            au.u[3] = pack2_bf16(e1 + e2, e1 - e2);  // HL,HH of cp1
            *(bf16x8*)&dst[(a_m0 + r) * PITCH + kofs] = au.v;
        }
    };

    auto stage_B = [&]() {
#pragma unroll
        for (int r = 0; r < 2; r++) {
            const f32x4 v0 = bf[r][0], v1 = bf[r][1];
            const f32x4 v2 = bf[r][2], v3 = bf[r][3];
            union { bf16x8 v; uint32_t u[4]; } b0, b1;
            b0.u[0] = pack2_bf16(v0[0], v1[0]);  // k=16jlq+0,1
            b0.u[1] = pack2_bf16(v2[0], v3[0]);  // k=16jlq+2,3
            b0.u[2] = pack2_bf16(v0[1], v1[1]);
            b0.u[3] = pack2_bf16(v2[1], v3[1]);
            b1.u[0] = pack2_bf16(v0[2], v1[2]);
            b1.u[1] = pack2_bf16(v2[2], v3[2]);
            b1.u[2] = pack2_bf16(v0[3], v1[3]);
            b1.u[3] = pack2_bf16(v2[3], v3[3]);
            short* br = &Bsh[(b_n + 32 * r) * PITCH + 16 * b_j];
            *(bf16x8*)(br)     = b0.v;
            *(bf16x8*)(br + 8) = b1.v;
        }
    };

    const int tm = wave & 3;     // m-tile within 64
    const int nh = wave >> 2;    // n-half
    f32x4 acc0 = (f32x4){0.f, 0.f, 0.f, 0.f};
    f32x4 acc1 = (f32x4){0.f, 0.f, 0.f, 0.f};

    auto mfma_chunk = [&](int buf) {
#pragma unroll
        for (int kh = 0; kh < 8; kh++) {
            const int ko = kh * 32 + l4 * 8;
            bf16x8 a   = *(const bf16x8*)&Ash[buf][(tm * 16 + l16) * PITCH + ko];
            bf16x8 bb0 = *(const bf16x8*)&Bsh[(nh * 32 + l16) * PITCH + ko];
            bf16x8 bb1 = *(const bf16x8*)&Bsh[(nh * 32 + 16 + l16) * PITCH + ko];
            acc0 = __builtin_amdgcn_mfma_f32_16x16x32_bf16(a, bb0, acc0, 0, 0, 0);
            acc1 = __builtin_amdgcn_mfma_f32_16x16x32_bf16(a, bb1, acc1, 0, 0, 0);
        }
    };

    load_A(0);
    load_B(0);
#pragma unroll 1
    for (int p = 0; p < 4; p++) {
        // ---- chunk 2p ----
        stage_A();                      // fills Ash[0] AND Ash[1]
        stage_B();                      // chunk 2p
        __syncthreads();
        if (p < 3) load_A(p + 1);       // ~2-chunk lead (covers HBM latency)
        load_B(2 * p + 1);
        mfma_chunk(0);
        __syncthreads();
        // ---- chunk 2p+1 ----
        stage_B();                      // chunk 2p+1
        __syncthreads();
        if (p < 3) load_B(2 * p + 2);
        mfma_chunk(1);
        __syncthreads();
    }

    // ---- write 64x64 fp32 partial, indexed by LOGICAL (widx,mh).
    // (C/D: col=lane&15, row=(lane>>4)*4+r)
    float* pp = part + (size_t)(widx * 4 + mh) * 4096;
#pragma unroll
    for (int r = 0; r < 4; r++) {
        const int m = tm * 16 + l4 * 4 + r;
        __builtin_nontemporal_store(acc0[r], &pp[m * 64 + nh * 32 + l16]);
        __builtin_nontemporal_store(acc1[r], &pp[m * 64 + nh * 32 + 16 + l16]);
    }
}

// out[m][n] = bias[n] + 0.5 * sum_{w=0}^{127} part[(w*4 + m>>6)][m&63][n]
__global__ __launch_bounds__(512) void wavelet_reduce(
    const float* __restrict__ part, const float* __restrict__ bias,
    float* __restrict__ out)
{
    __shared__ float red[8][64];
    const int m  = blockIdx.x;          // 256
    const int mh = m >> 6;
    const int ml = m & 63;
    const int n  = threadIdx.x & 63;
    const int g  = threadIdx.x >> 6;    // 8 groups
    const float* base = part + (size_t)mh * 4096 + ml * 64 + n;
    float acc = 0.f;
#pragma unroll 4
    for (int w = g; w < 128; w += 8)
        acc += base[(size_t)w * 16384];
    red[g][n] = acc;
    __syncthreads();
    if (g == 0) {
        const float v = (red[0][n] + red[1][n]) + (red[2][n] + red[3][n])
                      + (red[4][n] + red[5][n]) + (red[6][n] + red[7][n]);
        out[m * 64 + n] = 0.5f * v + bias[n];
    }
}

extern "C" void kernel_launch(void* const* d_in, const int* in_sizes, int n_in,
                              void* d_out, int out_size, void* d_ws, size_t ws_size,
                              hipStream_t stream)
{
    const float* x = (const float*)d_in[0];   // (256, 262144) fp32
    const float* W = (const float*)d_in[1];   // (64, 262144) fp32
    const float* b = (const float*)d_in[2];   // (64,) fp32
    float* out  = (float*)d_out;              // (256, 64) fp32
    float* part = (float*)d_ws;               // 512 * 16 KB = 8 MB (ws budget!)

    wavelet_gemm<<<512, 512, 0, stream>>>(x, W, part);
    wavelet_reduce<<<256, 512, 0, stream>>>(part, b, out);
}